// Round 13
// baseline (304.615 us; speedup 1.0000x reference)
//
#include <hip/hip_runtime.h>
#include <hip/hip_fp16.h>
#include <math.h>

#define N_NODES 50000
#define E_EDGES 800000
#define EPS_BN  1e-5f
#define INV_N   (1.0f / N_NODES)
#define SCAN_BLOCKS 196   // ceil(N_NODES/256)
#define QKV_BLOCKS  782   // ceil(N_NODES/64)
#define HIST_BLOCKS 3125  // ceil(E_EDGES/256)

// ---------------------------------------------------------------------------
// K1: fused QKV GEMM (+histogram blocks). 64-row register tile; Wq/Wk/Wv
// staged in LDS as fp16. Writes Q[N][64] fp32 and head-partitioned
// KV[head][node][16] fp16 (K in 0..7, V in 8..15) for XCD-local gathers.
// ---------------------------------------------------------------------------
__global__ __launch_bounds__(256) void qkv_hist_kernel(
    const float* __restrict__ h,
    const float* __restrict__ Wq, const float* __restrict__ bq,
    const float* __restrict__ Wk, const float* __restrict__ bk,
    const float* __restrict__ Wv, const float* __restrict__ bv,
    float* __restrict__ Q, __half* __restrict__ KV,
    const int* __restrict__ dst, int* __restrict__ count)
{
    __shared__ float  xs[64][68];     // 17.4 KB
    __shared__ __half Wqh[64][64];    // 8 KB
    __shared__ __half Wkh[64][64];    // 8 KB
    __shared__ __half Wvh[64][64];    // 8 KB
    const int t = threadIdx.x;

    if (blockIdx.x >= QKV_BLOCKS) {            // histogram blocks
        const int e = (blockIdx.x - QKV_BLOCKS) * 256 + t;
        if (e < E_EDGES) atomicAdd(&count[dst[e]], 1);
        return;
    }

    const int tx = t & 15;
    const int ty = t >> 4;
    const int row0 = blockIdx.x * 64;

    // stage weights fp32 -> fp16 LDS (coalesced float4)
    {
        __half2* wq = (__half2*)&Wqh[0][0];
        __half2* wk = (__half2*)&Wkh[0][0];
        __half2* wv = (__half2*)&Wvh[0][0];
        #pragma unroll
        for (int k = 0; k < 4; ++k) {
            const int i = t + k * 256;             // float4 index, 1024 total
            const float4 a = *(const float4*)(Wq + i * 4);
            wq[i * 2]     = __floats2half2_rn(a.x, a.y);
            wq[i * 2 + 1] = __floats2half2_rn(a.z, a.w);
            const float4 b = *(const float4*)(Wk + i * 4);
            wk[i * 2]     = __floats2half2_rn(b.x, b.y);
            wk[i * 2 + 1] = __floats2half2_rn(b.z, b.w);
            const float4 c = *(const float4*)(Wv + i * 4);
            wv[i * 2]     = __floats2half2_rn(c.x, c.y);
            wv[i * 2 + 1] = __floats2half2_rn(c.z, c.w);
        }
    }

    // stage x tile
    #pragma unroll
    for (int k = 0; k < 4; ++k) {
        const int i  = t + k * 256;
        const int r  = i >> 4;
        const int c4 = (i & 15) * 4;
        float4 v = make_float4(0.f, 0.f, 0.f, 0.f);
        if (row0 + r < N_NODES)
            v = *(const float4*)(h + (size_t)(row0 + r) * 64 + c4);
        *(float4*)(&xs[r][c4]) = v;
    }
    __syncthreads();

    const int c0 = tx * 4;
    float4 aq[4], ak[4], av[4];
    const float4 bq4 = *(const float4*)(bq + c0);
    const float4 bk4 = *(const float4*)(bk + c0);
    const float4 bv4 = *(const float4*)(bv + c0);
    #pragma unroll
    for (int i = 0; i < 4; ++i) { aq[i] = bq4; ak[i] = bk4; av[i] = bv4; }

    #pragma unroll 4
    for (int c = 0; c < 64; ++c) {
        const __half2* qp = (const __half2*)&Wqh[c][c0];
        const __half2* kp = (const __half2*)&Wkh[c][c0];
        const __half2* vp = (const __half2*)&Wvh[c][c0];
        const float2 wq0 = __half22float2(qp[0]);
        const float2 wq1 = __half22float2(qp[1]);
        const float2 wk0 = __half22float2(kp[0]);
        const float2 wk1 = __half22float2(kp[1]);
        const float2 wv0 = __half22float2(vp[0]);
        const float2 wv1 = __half22float2(vp[1]);
        #pragma unroll
        for (int i = 0; i < 4; ++i) {
            const float xv = xs[ty * 4 + i][c];
            aq[i].x = fmaf(xv, wq0.x, aq[i].x); aq[i].y = fmaf(xv, wq0.y, aq[i].y);
            aq[i].z = fmaf(xv, wq1.x, aq[i].z); aq[i].w = fmaf(xv, wq1.y, aq[i].w);
            ak[i].x = fmaf(xv, wk0.x, ak[i].x); ak[i].y = fmaf(xv, wk0.y, ak[i].y);
            ak[i].z = fmaf(xv, wk1.x, ak[i].z); ak[i].w = fmaf(xv, wk1.y, ak[i].w);
            av[i].x = fmaf(xv, wv0.x, av[i].x); av[i].y = fmaf(xv, wv0.y, av[i].y);
            av[i].z = fmaf(xv, wv1.x, av[i].z); av[i].w = fmaf(xv, wv1.y, av[i].w);
        }
    }
    #pragma unroll
    for (int i = 0; i < 4; ++i) {
        const int row = row0 + ty * 4 + i;
        if (row < N_NODES) {
            *(float4*)(Q + (size_t)row * 64 + c0) = aq[i];
            // head (c0>>3), within-head offset (c0&7): K at 0..7, V at 8..15
            __half* kvp = KV + ((size_t)(c0 >> 3) * N_NODES + row) * 16 + (c0 & 7);
            *(__half2*)(kvp)         = __floats2half2_rn(ak[i].x, ak[i].y);
            *(__half2*)(kvp + 2)     = __floats2half2_rn(ak[i].z, ak[i].w);
            *(__half2*)(kvp + 8)     = __floats2half2_rn(av[i].x, av[i].y);
            *(__half2*)(kvp + 8 + 2) = __floats2half2_rn(av[i].z, av[i].w);
        }
    }
}

// ---------------------------------------------------------------------------
// K2b-1: per-block scan -> block-local exclusive prefixes + block totals.
// ---------------------------------------------------------------------------
__global__ __launch_bounds__(256) void scanA_kernel(
    const int* __restrict__ count,
    int* __restrict__ rowStart, int* __restrict__ blockSums)
{
    __shared__ int ls[256];
    const int t = threadIdx.x;
    const int i = blockIdx.x * 256 + t;
    const int v = (i < N_NODES) ? count[i] : 0;
    ls[t] = v;
    __syncthreads();
    #pragma unroll
    for (int off = 1; off < 256; off <<= 1) {
        const int u = (t >= off) ? ls[t - off] : 0;
        __syncthreads();
        ls[t] += u;
        __syncthreads();
    }
    if (i < N_NODES) rowStart[i] = ls[t] - v;
    if (t == 255) blockSums[blockIdx.x] = ls[255];
}

// ---------------------------------------------------------------------------
// K2b-2: merged scanB+scanC.
// ---------------------------------------------------------------------------
__global__ __launch_bounds__(256) void scanBC_kernel(
    int* __restrict__ rowStart, int* __restrict__ cursor,
    const int* __restrict__ blockSums)
{
    __shared__ int ls[256];
    const int t = threadIdx.x;
    const int v = (t < SCAN_BLOCKS) ? blockSums[t] : 0;
    ls[t] = v;
    __syncthreads();
    #pragma unroll
    for (int off = 1; off < 256; off <<= 1) {
        const int u = (t >= off) ? ls[t - off] : 0;
        __syncthreads();
        ls[t] += u;
        __syncthreads();
    }
    const int exc = ls[t] - v;
    __syncthreads();
    ls[t] = exc;
    __syncthreads();
    const int boff = ls[blockIdx.x];
    const int i = blockIdx.x * 256 + t;
    if (i < N_NODES) {
        const int r = rowStart[i] + boff;
        rowStart[i] = r;
        cursor[i]   = r;
    }
    if (i == 0) rowStart[N_NODES] = E_EDGES;
}

// ---------------------------------------------------------------------------
// K2c: scatter src into dst-sorted order; 2 edges/thread, loads up front.
// ---------------------------------------------------------------------------
__global__ __launch_bounds__(256) void scatter_kernel(
    const int* __restrict__ src, const int* __restrict__ dst,
    int* __restrict__ cursor, int* __restrict__ srcSorted)
{
    const int e0 = blockIdx.x * 512 + threadIdx.x;
    const int e1 = e0 + 256;
    const bool h0 = e0 < E_EDGES;
    const bool h1 = e1 < E_EDGES;
    const int s0 = h0 ? src[e0] : 0;
    const int d0 = h0 ? dst[e0] : 0;
    const int s1 = h1 ? src[e1] : 0;
    const int d1 = h1 ? dst[e1] : 0;
    if (h0) srcSorted[atomicAdd(&cursor[d0], 1)] = s0;
    if (h1) srcSorted[atomicAdd(&cursor[d1], 1)] = s1;
}

// ---------------------------------------------------------------------------
// K3: head-partitioned gather. Block processes ONE head (blockIdx&7 -> XCD
// affinity; per-XCD KV working set = 1.6 MB, L2-resident). Grid = 2048:
// with the partitioned layout, more blocks add latency-hiding waves
// WITHOUT growing the per-XCD cached footprint (unlike R10's regression).
// ---------------------------------------------------------------------------
__global__ __launch_bounds__(256) void gather_edge_kernel(
    const float* __restrict__ h,
    const float* __restrict__ Q, const __half* __restrict__ KV,
    const int* __restrict__ rowStart, const int* __restrict__ srcSorted,
    float* __restrict__ x, float* __restrict__ s1, float* __restrict__ sq1)
{
    const int lane = threadIdx.x & 63;
    const int wave = threadIdx.x >> 6;
    const int slot = lane & 7;         // edge slot
    const int ns   = lane >> 3;        // node sub-index within wave
    const int hh   = blockIdx.x & 7;   // head == XCD slot
    const int chunk0  = blockIdx.x >> 3;
    const int nChunks = gridDim.x >> 3;
    const __half* __restrict__ KVh = KV + (size_t)hh * N_NODES * 16;

    float bsum[8], bsq[8];
    #pragma unroll
    for (int j = 0; j < 8; ++j) { bsum[j] = 0.0f; bsq[j] = 0.0f; }

    for (int chunk = chunk0; chunk * 32 < N_NODES; chunk += nChunks) {
        const int n = chunk * 32 + wave * 8 + ns;
        const bool valid = (n < N_NODES);
        int start = 0, end = 0;
        float4 q0 = make_float4(0.f, 0.f, 0.f, 0.f), q1 = q0;
        if (valid) {
            start = rowStart[n];
            end   = rowStart[n + 1];
            q0 = *(const float4*)(Q + (size_t)n * 64 + hh * 8);
            q1 = *(const float4*)(Q + (size_t)n * 64 + hh * 8 + 4);
        }
        float a0=0,a1=0,a2=0,a3=0,a4=0,a5=0,a6=0,a7=0,zacc=0;
        for (int e = start + slot; e < end; e += 16) {
            const int s0 = srcSorted[e];
            const int e1 = e + 8;
            const bool has1 = (e1 < end);
            const int s1i = has1 ? srcSorted[e1] : s0;
            const __half* kv0 = KVh + (size_t)s0 * 16;
            const __half* kv1 = KVh + (size_t)s1i * 16;
            const float4 kraw0 = *(const float4*)(kv0);       // K 8 halfs
            const float4 vraw0 = *(const float4*)(kv0 + 8);   // V 8 halfs
            const float4 kraw1 = *(const float4*)(kv1);
            const float4 vraw1 = *(const float4*)(kv1 + 8);

            {
                const __half2* kh = (const __half2*)&kraw0;
                const float2 ka = __half22float2(kh[0]);
                const float2 kb = __half22float2(kh[1]);
                const float2 kc = __half22float2(kh[2]);
                const float2 kd = __half22float2(kh[3]);
                float sc = ka.x*q0.x + ka.y*q0.y + kb.x*q0.z + kb.y*q0.w
                         + kc.x*q1.x + kc.y*q1.y + kd.x*q1.z + kd.y*q1.w;
                sc *= 0.35355339059327373f;
                sc = fminf(5.0f, fmaxf(-5.0f, sc));
                const float p = __expf(sc);
                const __half2* vh = (const __half2*)&vraw0;
                const float2 va = __half22float2(vh[0]);
                const float2 vb = __half22float2(vh[1]);
                const float2 vc = __half22float2(vh[2]);
                const float2 vd = __half22float2(vh[3]);
                a0 = fmaf(p, va.x, a0); a1 = fmaf(p, va.y, a1);
                a2 = fmaf(p, vb.x, a2); a3 = fmaf(p, vb.y, a3);
                a4 = fmaf(p, vc.x, a4); a5 = fmaf(p, vc.y, a5);
                a6 = fmaf(p, vd.x, a6); a7 = fmaf(p, vd.y, a7);
                zacc += p;
            }
            if (has1) {
                const __half2* kh = (const __half2*)&kraw1;
                const float2 ka = __half22float2(kh[0]);
                const float2 kb = __half22float2(kh[1]);
                const float2 kc = __half22float2(kh[2]);
                const float2 kd = __half22float2(kh[3]);
                float sc = ka.x*q0.x + ka.y*q0.y + kb.x*q0.z + kb.y*q0.w
                         + kc.x*q1.x + kc.y*q1.y + kd.x*q1.z + kd.y*q1.w;
                sc *= 0.35355339059327373f;
                sc = fminf(5.0f, fmaxf(-5.0f, sc));
                const float p = __expf(sc);
                const __half2* vh = (const __half2*)&vraw1;
                const float2 va = __half22float2(vh[0]);
                const float2 vb = __half22float2(vh[1]);
                const float2 vc = __half22float2(vh[2]);
                const float2 vd = __half22float2(vh[3]);
                a0 = fmaf(p, va.x, a0); a1 = fmaf(p, va.y, a1);
                a2 = fmaf(p, vb.x, a2); a3 = fmaf(p, vb.y, a3);
                a4 = fmaf(p, vc.x, a4); a5 = fmaf(p, vc.y, a5);
                a6 = fmaf(p, vd.x, a6); a7 = fmaf(p, vd.y, a7);
                zacc += p;
            }
        }
        // reduce across the 8 slots (lane bits 0..2)
        #pragma unroll
        for (int m = 1; m < 8; m <<= 1) {
            a0 += __shfl_xor(a0, m, 64); a1 += __shfl_xor(a1, m, 64);
            a2 += __shfl_xor(a2, m, 64); a3 += __shfl_xor(a3, m, 64);
            a4 += __shfl_xor(a4, m, 64); a5 += __shfl_xor(a5, m, 64);
            a6 += __shfl_xor(a6, m, 64); a7 += __shfl_xor(a7, m, 64);
            zacc += __shfl_xor(zacc, m, 64);
        }
        if (slot == 0 && valid) {
            const float inv = (zacc == 0.0f) ? 0.0f : 1.0f / zacc;
            const float4 h0 = *(const float4*)(h + (size_t)n * 64 + hh * 8);
            const float4 h1 = *(const float4*)(h + (size_t)n * 64 + hh * 8 + 4);
            float xv[8];
            xv[0] = fmaf(a0, inv, h0.x); xv[1] = fmaf(a1, inv, h0.y);
            xv[2] = fmaf(a2, inv, h0.z); xv[3] = fmaf(a3, inv, h0.w);
            xv[4] = fmaf(a4, inv, h1.x); xv[5] = fmaf(a5, inv, h1.y);
            xv[6] = fmaf(a6, inv, h1.z); xv[7] = fmaf(a7, inv, h1.w);
            *(float4*)(x + (size_t)n * 64 + hh * 8)     =
                make_float4(xv[0], xv[1], xv[2], xv[3]);
            *(float4*)(x + (size_t)n * 64 + hh * 8 + 4) =
                make_float4(xv[4], xv[5], xv[6], xv[7]);
            #pragma unroll
            for (int j = 0; j < 8; ++j) {
                bsum[j] += xv[j];
                bsq[j]  += xv[j] * xv[j];
            }
        }
    }
    // block BN1 partials for this head's 8 channels
    __shared__ float lsm[32][8];
    __shared__ float lsq[32][8];
    if (slot == 0) {
        #pragma unroll
        for (int j = 0; j < 8; ++j) {
            lsm[wave * 8 + ns][j] = bsum[j];
            lsq[wave * 8 + ns][j] = bsq[j];
        }
    }
    __syncthreads();
    if (threadIdx.x < 8) {
        const int tt = threadIdx.x;
        float ss = 0.f, qq = 0.f;
        #pragma unroll
        for (int k = 0; k < 32; ++k) { ss += lsm[k][tt]; qq += lsq[k][tt]; }
        atomicAdd(s1 + hh * 8 + tt, ss);
        atomicAdd(sq1 + hh * 8 + tt, qq);
    }
}

// ---------------------------------------------------------------------------
// K5: fused BN1-finalize+apply + FFN + residual + BN2 partials.
// 512 thr, 64-row tile. W1/W2/hidden staged in LDS as fp16. 64 KB LDS.
// ---------------------------------------------------------------------------
__global__ __launch_bounds__(512, 4) void ffn_kernel(
    const float* __restrict__ x,
    const float* __restrict__ s1, const float* __restrict__ sq1,
    const float* __restrict__ g1, const float* __restrict__ b1,
    const float* __restrict__ W1, const float* __restrict__ bb1,
    const float* __restrict__ W2, const float* __restrict__ bb2,
    float* __restrict__ y, float* __restrict__ s2, float* __restrict__ sq2)
{
    __shared__ __half W1h[64][128];   // 16 KB (also reused as BN2 scratch)
    __shared__ __half W2h[128][64];   // 16 KB
    __shared__ float  xs[64][64];     // 16 KB
    __shared__ __half ts[64][128];    // 16 KB

    const int t  = threadIdx.x;
    const int tx = t & 15;
    const int ty = t >> 4;
    const int row0 = blockIdx.x * 64;

    {
        __half2* w1p = (__half2*)&W1h[0][0];
        __half2* w2p = (__half2*)&W2h[0][0];
        #pragma unroll
        for (int k = 0; k < 4; ++k) {
            const int i = t + k * 512;
            const float4 w1 = *(const float4*)(W1 + i * 4);
            w1p[i * 2]     = __floats2half2_rn(w1.x, w1.y);
            w1p[i * 2 + 1] = __floats2half2_rn(w1.z, w1.w);
            const float4 w2 = *(const float4*)(W2 + i * 4);
            w2p[i * 2]     = __floats2half2_rn(w2.x, w2.y);
            w2p[i * 2 + 1] = __floats2half2_rn(w2.z, w2.w);
        }
    }

    {
        const int c4 = tx * 4;
        const float4 ssum = *(const float4*)(s1 + c4);
        const float4 sqs  = *(const float4*)(sq1 + c4);
        const float4 gg   = *(const float4*)(g1 + c4);
        const float4 bb   = *(const float4*)(b1 + c4);
        float4 mm, rr, A, C;
        mm.x = ssum.x * INV_N; mm.y = ssum.y * INV_N;
        mm.z = ssum.z * INV_N; mm.w = ssum.w * INV_N;
        rr.x = rsqrtf(sqs.x * INV_N - mm.x * mm.x + EPS_BN);
        rr.y = rsqrtf(sqs.y * INV_N - mm.y * mm.y + EPS_BN);
        rr.z = rsqrtf(sqs.z * INV_N - mm.z * mm.z + EPS_BN);
        rr.w = rsqrtf(sqs.w * INV_N - mm.w * mm.w + EPS_BN);
        A.x = rr.x * gg.x; C.x = bb.x - mm.x * A.x;
        A.y = rr.y * gg.y; C.y = bb.y - mm.y * A.y;
        A.z = rr.z * gg.z; C.z = bb.z - mm.z * A.z;
        A.w = rr.w * gg.w; C.w = bb.w - mm.w * A.w;
        #pragma unroll
        for (int k = 0; k < 2; ++k) {
            const int i = t + k * 512;
            const int r = i >> 4;
            float4 v = make_float4(0.f, 0.f, 0.f, 0.f);
            if (row0 + r < N_NODES) {
                const float4 xv = *(const float4*)(x + (size_t)(row0 + r) * 64 + c4);
                v.x = fmaf(xv.x, A.x, C.x);
                v.y = fmaf(xv.y, A.y, C.y);
                v.z = fmaf(xv.z, A.z, C.z);
                v.w = fmaf(xv.w, A.w, C.w);
            }
            *(float4*)(&xs[r][c4]) = v;
        }
    }
    __syncthreads();

    const int r0 = ty * 2, r1 = r0 + 1;

    {
        const int cA = tx * 4, cB = 64 + tx * 4;
        float4 aA0 = make_float4(0,0,0,0), aA1 = aA0, aB0 = aA0, aB1 = aA0;
        #pragma unroll 4
        for (int c = 0; c < 64; ++c) {
            const __half2* wAp = (const __half2*)&W1h[c][cA];
            const __half2* wBp = (const __half2*)&W1h[c][cB];
            const float2 wa0 = __half22float2(wAp[0]);
            const float2 wa1 = __half22float2(wAp[1]);
            const float2 wb0 = __half22float2(wBp[0]);
            const float2 wb1 = __half22float2(wBp[1]);
            const float x0 = xs[r0][c];
            const float x1 = xs[r1][c];
            aA0.x = fmaf(x0, wa0.x, aA0.x); aA0.y = fmaf(x0, wa0.y, aA0.y);
            aA0.z = fmaf(x0, wa1.x, aA0.z); aA0.w = fmaf(x0, wa1.y, aA0.w);
            aA1.x = fmaf(x1, wa0.x, aA1.x); aA1.y = fmaf(x1, wa0.y, aA1.y);
            aA1.z = fmaf(x1, wa1.x, aA1.z); aA1.w = fmaf(x1, wa1.y, aA1.w);
            aB0.x = fmaf(x0, wb0.x, aB0.x); aB0.y = fmaf(x0, wb0.y, aB0.y);
            aB0.z = fmaf(x0, wb1.x, aB0.z); aB0.w = fmaf(x0, wb1.y, aB0.w);
            aB1.x = fmaf(x1, wb0.x, aB1.x); aB1.y = fmaf(x1, wb0.y, aB1.y);
            aB1.z = fmaf(x1, wb1.x, aB1.z); aB1.w = fmaf(x1, wb1.y, aB1.w);
        }
        const float4 b1A = *(const float4*)(bb1 + cA);
        const float4 b1B = *(const float4*)(bb1 + cB);
        aA0.x = fmaxf(aA0.x + b1A.x, 0.f); aA0.y = fmaxf(aA0.y + b1A.y, 0.f);
        aA0.z = fmaxf(aA0.z + b1A.z, 0.f); aA0.w = fmaxf(aA0.w + b1A.w, 0.f);
        aA1.x = fmaxf(aA1.x + b1A.x, 0.f); aA1.y = fmaxf(aA1.y + b1A.y, 0.f);
        aA1.z = fmaxf(aA1.z + b1A.z, 0.f); aA1.w = fmaxf(aA1.w + b1A.w, 0.f);
        aB0.x = fmaxf(aB0.x + b1B.x, 0.f); aB0.y = fmaxf(aB0.y + b1B.y, 0.f);
        aB0.z = fmaxf(aB0.z + b1B.z, 0.f); aB0.w = fmaxf(aB0.w + b1B.w, 0.f);
        aB1.x = fmaxf(aB1.x + b1B.x, 0.f); aB1.y = fmaxf(aB1.y + b1B.y, 0.f);
        aB1.z = fmaxf(aB1.z + b1B.z, 0.f); aB1.w = fmaxf(aB1.w + b1B.w, 0.f);
        *(__half2*)&ts[r0][cA]     = __floats2half2_rn(aA0.x, aA0.y);
        *(__half2*)&ts[r0][cA + 2] = __floats2half2_rn(aA0.z, aA0.w);
        *(__half2*)&ts[r1][cA]     = __floats2half2_rn(aA1.x, aA1.y);
        *(__half2*)&ts[r1][cA + 2] = __floats2half2_rn(aA1.z, aA1.w);
        *(__half2*)&ts[r0][cB]     = __floats2half2_rn(aB0.x, aB0.y);
        *(__half2*)&ts[r0][cB + 2] = __floats2half2_rn(aB0.z, aB0.w);
        *(__half2*)&ts[r1][cB]     = __floats2half2_rn(aB1.x, aB1.y);
        *(__half2*)&ts[r1][cB + 2] = __floats2half2_rn(aB1.z, aB1.w);
    }
    __syncthreads();

    float4 s = make_float4(0,0,0,0), q = s;
    {
        const int c4 = tx * 4;
        float4 y0 = make_float4(0,0,0,0), y1 = y0;
        #pragma unroll 4
        for (int k = 0; k < 128; ++k) {
            const __half2* wp = (const __half2*)&W2h[k][c4];
            const float2 wa = __half22float2(wp[0]);
            const float2 wb = __half22float2(wp[1]);
            const float T0 = __half2float(ts[r0][k]);
            const float T1 = __half2float(ts[r1][k]);
            y0.x = fmaf(T0, wa.x, y0.x); y0.y = fmaf(T0, wa.y, y0.y);
            y0.z = fmaf(T0, wb.x, y0.z); y0.w = fmaf(T0, wb.y, y0.w);
            y1.x = fmaf(T1, wa.x, y1.x); y1.y = fmaf(T1, wa.y, y1.y);
            y1.z = fmaf(T1, wb.x, y1.z); y1.w = fmaf(T1, wb.y, y1.w);
        }
        const float4 bb = *(const float4*)(bb2 + c4);
        const float4 h0 = *(const float4*)(&xs[r0][c4]);
        const float4 h1v = *(const float4*)(&xs[r1][c4]);
        y0.x += bb.x + h0.x;  y0.y += bb.y + h0.y;
        y0.z += bb.z + h0.z;  y0.w += bb.w + h0.w;
        y1.x += bb.x + h1v.x; y1.y += bb.y + h1v.y;
        y1.z += bb.z + h1v.z; y1.w += bb.w + h1v.w;

        const bool v0 = (row0 + r0) < N_NODES;
        const bool v1 = (row0 + r1) < N_NODES;
        if (v0) *(float4*)(y + (size_t)(row0 + r0) * 64 + c4) = y0;
        if (v1) *(float4*)(y + (size_t)(row0 + r1) * 64 + c4) = y1;

        if (v0) {
            s.x += y0.x; s.y += y0.y; s.z += y0.z; s.w += y0.w;
            q.x += y0.x*y0.x; q.y += y0.y*y0.y; q.z += y0.z*y0.z; q.w += y0.w*y0.w;
        }
        if (v1) {
            s.x += y1.x; s.y += y1.y; s.z += y1.z; s.w += y1.w;
            q.x += y1.x*y1.x; q.y += y1.y*y1.y; q.z += y1.z*y1.z; q.w += y1.w*y1.w;
        }
    }
    {
        float* red = (float*)&W1h[0][0];
        const int c4 = tx * 4;
        *(float4*)(red + ty * 64 + c4)        = s;
        *(float4*)(red + (32 + ty) * 64 + c4) = q;
    }
    __syncthreads();
    if (t < 64) {
        const float* red = (const float*)&W1h[0][0];
        float ss = 0.f, qq = 0.f;
        #pragma unroll
        for (int k = 0; k < 32; ++k) {
            ss += red[k * 64 + t];
            qq += red[(32 + k) * 64 + t];
        }
        atomicAdd(s2 + t, ss);
        atomicAdd(sq2 + t, qq);
    }
}

// ---------------------------------------------------------------------------
// K6: BN2 finalize + apply in place on y, float4.
// ---------------------------------------------------------------------------
__global__ __launch_bounds__(256) void bn2_apply_kernel(
    float* __restrict__ y,
    const float* __restrict__ s2, const float* __restrict__ sq2,
    const float* __restrict__ g2, const float* __restrict__ b2)
{
    const int c4 = (threadIdx.x & 15) * 4;
    const float4 ssum = *(const float4*)(s2 + c4);
    const float4 sqs  = *(const float4*)(sq2 + c4);
    const float4 gg   = *(const float4*)(g2 + c4);
    const float4 bb   = *(const float4*)(b2 + c4);
    float4 mm, rr, A, C;
    mm.x = ssum.x * INV_N; mm.y = ssum.y * INV_N;
    mm.z = ssum.z * INV_N; mm.w = ssum.w * INV_N;
    rr.x = rsqrtf(sqs.x * INV_N - mm.x * mm.x + EPS_BN);
    rr.y = rsqrtf(sqs.y * INV_N - mm.y * mm.y + EPS_BN);
    rr.z = rsqrtf(sqs.z * INV_N - mm.z * mm.z + EPS_BN);
    rr.w = rsqrtf(sqs.w * INV_N - mm.w * mm.w + EPS_BN);
    A.x = rr.x * gg.x; C.x = bb.x - mm.x * A.x;
    A.y = rr.y * gg.y; C.y = bb.y - mm.y * A.y;
    A.z = rr.z * gg.z; C.z = bb.z - mm.z * A.z;
    A.w = rr.w * gg.w; C.w = bb.w - mm.w * A.w;

    const int total4 = N_NODES * 16;
    const int stride = gridDim.x * blockDim.x;    // multiple of 16
    for (int i = blockIdx.x * blockDim.x + threadIdx.x; i < total4; i += stride) {
        float4 v = *((float4*)y + i);
        v.x = fmaf(v.x, A.x, C.x);
        v.y = fmaf(v.y, A.y, C.y);
        v.z = fmaf(v.z, A.z, C.z);
        v.w = fmaf(v.w, A.w, C.w);
        *((float4*)y + i) = v;
    }
}

extern "C" void kernel_launch(void* const* d_in, const int* in_sizes, int n_in,
                              void* d_out, int out_size, void* d_ws, size_t ws_size,
                              hipStream_t stream)
{
    const float* h   = (const float*)d_in[0];
    const int*   src = (const int*)d_in[1];
    const int*   dst = (const int*)d_in[2];
    const float* Wq  = (const float*)d_in[3];
    const float* bq  = (const float*)d_in[4];
    const float* Wk  = (const float*)d_in[5];
    const float* bk  = (const float*)d_in[6];
    const float* Wv  = (const float*)d_in[7];
    const float* bv  = (const float*)d_in[8];
    const float* g1  = (const float*)d_in[9];
    const float* b1  = (const float*)d_in[10];
    const float* W1  = (const float*)d_in[11];
    const float* bb1 = (const float*)d_in[12];
    const float* W2  = (const float*)d_in[13];
    const float* bb2 = (const float*)d_in[14];
    const float* g2  = (const float*)d_in[15];
    const float* b2  = (const float*)d_in[16];
    float* out = (float*)d_out;

    float* ws = (float*)d_ws;
    const size_t ND = (size_t)N_NODES * 64;
    float* Q  = ws;            // reused as x (per-head ranges, same-block order)
    __half* KV = (__half*)(ws + ND);   // fp16 KV[8][N][16]
    float* x  = Q;
    int* srcSorted = (int*)(ws + 3 * ND);          // E
    int* count     = srcSorted + E_EDGES;          // N   (zeroed)
    float* st      = (float*)(count + N_NODES);    // 512 floats (zeroed)
    int* rowStart  = (int*)(st + 512);             // N+1
    int* cursor    = rowStart + N_NODES + 1;       // N
    int* blockSums = cursor + N_NODES;             // SCAN_BLOCKS
    float* s1 = st,       *sq1 = st + 64;
    float* s2 = st + 256, *sq2 = st + 320;

    hipMemsetAsync(count, 0, (N_NODES + 512) * sizeof(int), stream);

    qkv_hist_kernel<<<QKV_BLOCKS + HIST_BLOCKS, 256, 0, stream>>>(
        h, Wq, bq, Wk, bk, Wv, bv, Q, KV, dst, count);
    scanA_kernel<<<SCAN_BLOCKS, 256, 0, stream>>>(count, rowStart, blockSums);
    scanBC_kernel<<<SCAN_BLOCKS, 256, 0, stream>>>(rowStart, cursor, blockSums);
    scatter_kernel<<<(E_EDGES + 511) / 512, 256, 0, stream>>>(
        src, dst, cursor, srcSorted);
    gather_edge_kernel<<<2048, 256, 0, stream>>>(h, Q, KV, rowStart, srcSorted,
                                                 x, s1, sq1);
    ffn_kernel<<<(N_NODES + 63) / 64, 512, 0, stream>>>(
        x, s1, sq1, g1, b1, W1, bb1, W2, bb2, out, s2, sq2);
    bn2_apply_kernel<<<2048, 256, 0, stream>>>(out, s2, sq2, g2, b2);
}

// Round 14
// 293.300 us; speedup vs baseline: 1.0386x; 1.0386x over previous
//
#include <hip/hip_runtime.h>
#include <hip/hip_fp16.h>
#include <math.h>

#define N_NODES 50000
#define E_EDGES 800000
#define EPS_BN  1e-5f
#define INV_N   (1.0f / N_NODES)
#define SCAN_BLOCKS 196   // ceil(N_NODES/256)
#define QKV_BLOCKS  782   // ceil(N_NODES/64)
#define HIST_BLOCKS 3125  // ceil(E_EDGES/256)

// ---------------------------------------------------------------------------
// K1: fused QKV GEMM (+histogram blocks). 64-row register tile; Wq/Wk/Wv
// staged in LDS as fp16. Writes Q[N][64] fp32 and head-partitioned
// KV[head][node][16] fp16 (K in 0..7, V in 8..15) for XCD-local gathers.
// ---------------------------------------------------------------------------
__global__ __launch_bounds__(256) void qkv_hist_kernel(
    const float* __restrict__ h,
    const float* __restrict__ Wq, const float* __restrict__ bq,
    const float* __restrict__ Wk, const float* __restrict__ bk,
    const float* __restrict__ Wv, const float* __restrict__ bv,
    float* __restrict__ Q, __half* __restrict__ KV,
    const int* __restrict__ dst, int* __restrict__ count)
{
    __shared__ float  xs[64][68];     // 17.4 KB
    __shared__ __half Wqh[64][64];    // 8 KB
    __shared__ __half Wkh[64][64];    // 8 KB
    __shared__ __half Wvh[64][64];    // 8 KB
    const int t = threadIdx.x;

    if (blockIdx.x >= QKV_BLOCKS) {            // histogram blocks
        const int e = (blockIdx.x - QKV_BLOCKS) * 256 + t;
        if (e < E_EDGES) atomicAdd(&count[dst[e]], 1);
        return;
    }

    const int tx = t & 15;
    const int ty = t >> 4;
    const int row0 = blockIdx.x * 64;

    // stage weights fp32 -> fp16 LDS (coalesced float4)
    {
        __half2* wq = (__half2*)&Wqh[0][0];
        __half2* wk = (__half2*)&Wkh[0][0];
        __half2* wv = (__half2*)&Wvh[0][0];
        #pragma unroll
        for (int k = 0; k < 4; ++k) {
            const int i = t + k * 256;             // float4 index, 1024 total
            const float4 a = *(const float4*)(Wq + i * 4);
            wq[i * 2]     = __floats2half2_rn(a.x, a.y);
            wq[i * 2 + 1] = __floats2half2_rn(a.z, a.w);
            const float4 b = *(const float4*)(Wk + i * 4);
            wk[i * 2]     = __floats2half2_rn(b.x, b.y);
            wk[i * 2 + 1] = __floats2half2_rn(b.z, b.w);
            const float4 c = *(const float4*)(Wv + i * 4);
            wv[i * 2]     = __floats2half2_rn(c.x, c.y);
            wv[i * 2 + 1] = __floats2half2_rn(c.z, c.w);
        }
    }

    // stage x tile
    #pragma unroll
    for (int k = 0; k < 4; ++k) {
        const int i  = t + k * 256;
        const int r  = i >> 4;
        const int c4 = (i & 15) * 4;
        float4 v = make_float4(0.f, 0.f, 0.f, 0.f);
        if (row0 + r < N_NODES)
            v = *(const float4*)(h + (size_t)(row0 + r) * 64 + c4);
        *(float4*)(&xs[r][c4]) = v;
    }
    __syncthreads();

    const int c0 = tx * 4;
    float4 aq[4], ak[4], av[4];
    const float4 bq4 = *(const float4*)(bq + c0);
    const float4 bk4 = *(const float4*)(bk + c0);
    const float4 bv4 = *(const float4*)(bv + c0);
    #pragma unroll
    for (int i = 0; i < 4; ++i) { aq[i] = bq4; ak[i] = bk4; av[i] = bv4; }

    #pragma unroll 4
    for (int c = 0; c < 64; ++c) {
        const __half2* qp = (const __half2*)&Wqh[c][c0];
        const __half2* kp = (const __half2*)&Wkh[c][c0];
        const __half2* vp = (const __half2*)&Wvh[c][c0];
        const float2 wq0 = __half22float2(qp[0]);
        const float2 wq1 = __half22float2(qp[1]);
        const float2 wk0 = __half22float2(kp[0]);
        const float2 wk1 = __half22float2(kp[1]);
        const float2 wv0 = __half22float2(vp[0]);
        const float2 wv1 = __half22float2(vp[1]);
        #pragma unroll
        for (int i = 0; i < 4; ++i) {
            const float xv = xs[ty * 4 + i][c];
            aq[i].x = fmaf(xv, wq0.x, aq[i].x); aq[i].y = fmaf(xv, wq0.y, aq[i].y);
            aq[i].z = fmaf(xv, wq1.x, aq[i].z); aq[i].w = fmaf(xv, wq1.y, aq[i].w);
            ak[i].x = fmaf(xv, wk0.x, ak[i].x); ak[i].y = fmaf(xv, wk0.y, ak[i].y);
            ak[i].z = fmaf(xv, wk1.x, ak[i].z); ak[i].w = fmaf(xv, wk1.y, ak[i].w);
            av[i].x = fmaf(xv, wv0.x, av[i].x); av[i].y = fmaf(xv, wv0.y, av[i].y);
            av[i].z = fmaf(xv, wv1.x, av[i].z); av[i].w = fmaf(xv, wv1.y, av[i].w);
        }
    }
    #pragma unroll
    for (int i = 0; i < 4; ++i) {
        const int row = row0 + ty * 4 + i;
        if (row < N_NODES) {
            *(float4*)(Q + (size_t)row * 64 + c0) = aq[i];
            // head (c0>>3), within-head offset (c0&7): K at 0..7, V at 8..15
            __half* kvp = KV + ((size_t)(c0 >> 3) * N_NODES + row) * 16 + (c0 & 7);
            *(__half2*)(kvp)         = __floats2half2_rn(ak[i].x, ak[i].y);
            *(__half2*)(kvp + 2)     = __floats2half2_rn(ak[i].z, ak[i].w);
            *(__half2*)(kvp + 8)     = __floats2half2_rn(av[i].x, av[i].y);
            *(__half2*)(kvp + 8 + 2) = __floats2half2_rn(av[i].z, av[i].w);
        }
    }
}

// ---------------------------------------------------------------------------
// K2b-1: per-block scan -> block-local exclusive prefixes + block totals.
// ---------------------------------------------------------------------------
__global__ __launch_bounds__(256) void scanA_kernel(
    const int* __restrict__ count,
    int* __restrict__ rowStart, int* __restrict__ blockSums)
{
    __shared__ int ls[256];
    const int t = threadIdx.x;
    const int i = blockIdx.x * 256 + t;
    const int v = (i < N_NODES) ? count[i] : 0;
    ls[t] = v;
    __syncthreads();
    #pragma unroll
    for (int off = 1; off < 256; off <<= 1) {
        const int u = (t >= off) ? ls[t - off] : 0;
        __syncthreads();
        ls[t] += u;
        __syncthreads();
    }
    if (i < N_NODES) rowStart[i] = ls[t] - v;
    if (t == 255) blockSums[blockIdx.x] = ls[255];
}

// ---------------------------------------------------------------------------
// K2b-2: merged scanB+scanC.
// ---------------------------------------------------------------------------
__global__ __launch_bounds__(256) void scanBC_kernel(
    int* __restrict__ rowStart, int* __restrict__ cursor,
    const int* __restrict__ blockSums)
{
    __shared__ int ls[256];
    const int t = threadIdx.x;
    const int v = (t < SCAN_BLOCKS) ? blockSums[t] : 0;
    ls[t] = v;
    __syncthreads();
    #pragma unroll
    for (int off = 1; off < 256; off <<= 1) {
        const int u = (t >= off) ? ls[t - off] : 0;
        __syncthreads();
        ls[t] += u;
        __syncthreads();
    }
    const int exc = ls[t] - v;
    __syncthreads();
    ls[t] = exc;
    __syncthreads();
    const int boff = ls[blockIdx.x];
    const int i = blockIdx.x * 256 + t;
    if (i < N_NODES) {
        const int r = rowStart[i] + boff;
        rowStart[i] = r;
        cursor[i]   = r;
    }
    if (i == 0) rowStart[N_NODES] = E_EDGES;
}

// ---------------------------------------------------------------------------
// K2c: scatter src (as uint16) into dst-sorted order; 2 edges/thread.
// ---------------------------------------------------------------------------
__global__ __launch_bounds__(256) void scatter_kernel(
    const int* __restrict__ src, const int* __restrict__ dst,
    int* __restrict__ cursor, unsigned short* __restrict__ srcSorted)
{
    const int e0 = blockIdx.x * 512 + threadIdx.x;
    const int e1 = e0 + 256;
    const bool h0 = e0 < E_EDGES;
    const bool h1 = e1 < E_EDGES;
    const int s0 = h0 ? src[e0] : 0;
    const int d0 = h0 ? dst[e0] : 0;
    const int s1 = h1 ? src[e1] : 0;
    const int d1 = h1 ? dst[e1] : 0;
    if (h0) srcSorted[atomicAdd(&cursor[d0], 1)] = (unsigned short)s0;
    if (h1) srcSorted[atomicAdd(&cursor[d1], 1)] = (unsigned short)s1;
}

// ---------------------------------------------------------------------------
// K3: head-partitioned gather. Block processes ONE head (blockIdx&7 -> XCD
// affinity; per-XCD KV working set = 1.6 MB, L2-resident). Grid = 1024:
// measured optimum (2048 regressed twice: R10 83us interleaved, R13 64us
// partitioned -> L2 request-queue saturation, not wave starvation).
// srcSorted is uint16 (halves index-stream traffic).
// ---------------------------------------------------------------------------
__global__ __launch_bounds__(256) void gather_edge_kernel(
    const float* __restrict__ h,
    const float* __restrict__ Q, const __half* __restrict__ KV,
    const int* __restrict__ rowStart, const unsigned short* __restrict__ srcSorted,
    float* __restrict__ x, float* __restrict__ s1, float* __restrict__ sq1)
{
    const int lane = threadIdx.x & 63;
    const int wave = threadIdx.x >> 6;
    const int slot = lane & 7;         // edge slot
    const int ns   = lane >> 3;        // node sub-index within wave
    const int hh   = blockIdx.x & 7;   // head == XCD slot
    const int chunk0  = blockIdx.x >> 3;
    const int nChunks = gridDim.x >> 3;
    const __half* __restrict__ KVh = KV + (size_t)hh * N_NODES * 16;

    float bsum[8], bsq[8];
    #pragma unroll
    for (int j = 0; j < 8; ++j) { bsum[j] = 0.0f; bsq[j] = 0.0f; }

    for (int chunk = chunk0; chunk * 32 < N_NODES; chunk += nChunks) {
        const int n = chunk * 32 + wave * 8 + ns;
        const bool valid = (n < N_NODES);
        int start = 0, end = 0;
        float4 q0 = make_float4(0.f, 0.f, 0.f, 0.f), q1 = q0;
        if (valid) {
            start = rowStart[n];
            end   = rowStart[n + 1];
            q0 = *(const float4*)(Q + (size_t)n * 64 + hh * 8);
            q1 = *(const float4*)(Q + (size_t)n * 64 + hh * 8 + 4);
        }
        float a0=0,a1=0,a2=0,a3=0,a4=0,a5=0,a6=0,a7=0,zacc=0;
        for (int e = start + slot; e < end; e += 16) {
            const int s0 = srcSorted[e];
            const int e1 = e + 8;
            const bool has1 = (e1 < end);
            const int s1i = has1 ? (int)srcSorted[e1] : s0;
            const __half* kv0 = KVh + (size_t)s0 * 16;
            const __half* kv1 = KVh + (size_t)s1i * 16;
            const float4 kraw0 = *(const float4*)(kv0);       // K 8 halfs
            const float4 vraw0 = *(const float4*)(kv0 + 8);   // V 8 halfs
            const float4 kraw1 = *(const float4*)(kv1);
            const float4 vraw1 = *(const float4*)(kv1 + 8);

            {
                const __half2* kh = (const __half2*)&kraw0;
                const float2 ka = __half22float2(kh[0]);
                const float2 kb = __half22float2(kh[1]);
                const float2 kc = __half22float2(kh[2]);
                const float2 kd = __half22float2(kh[3]);
                float sc = ka.x*q0.x + ka.y*q0.y + kb.x*q0.z + kb.y*q0.w
                         + kc.x*q1.x + kc.y*q1.y + kd.x*q1.z + kd.y*q1.w;
                sc *= 0.35355339059327373f;
                sc = fminf(5.0f, fmaxf(-5.0f, sc));
                const float p = __expf(sc);
                const __half2* vh = (const __half2*)&vraw0;
                const float2 va = __half22float2(vh[0]);
                const float2 vb = __half22float2(vh[1]);
                const float2 vc = __half22float2(vh[2]);
                const float2 vd = __half22float2(vh[3]);
                a0 = fmaf(p, va.x, a0); a1 = fmaf(p, va.y, a1);
                a2 = fmaf(p, vb.x, a2); a3 = fmaf(p, vb.y, a3);
                a4 = fmaf(p, vc.x, a4); a5 = fmaf(p, vc.y, a5);
                a6 = fmaf(p, vd.x, a6); a7 = fmaf(p, vd.y, a7);
                zacc += p;
            }
            if (has1) {
                const __half2* kh = (const __half2*)&kraw1;
                const float2 ka = __half22float2(kh[0]);
                const float2 kb = __half22float2(kh[1]);
                const float2 kc = __half22float2(kh[2]);
                const float2 kd = __half22float2(kh[3]);
                float sc = ka.x*q0.x + ka.y*q0.y + kb.x*q0.z + kb.y*q0.w
                         + kc.x*q1.x + kc.y*q1.y + kd.x*q1.z + kd.y*q1.w;
                sc *= 0.35355339059327373f;
                sc = fminf(5.0f, fmaxf(-5.0f, sc));
                const float p = __expf(sc);
                const __half2* vh = (const __half2*)&vraw1;
                const float2 va = __half22float2(vh[0]);
                const float2 vb = __half22float2(vh[1]);
                const float2 vc = __half22float2(vh[2]);
                const float2 vd = __half22float2(vh[3]);
                a0 = fmaf(p, va.x, a0); a1 = fmaf(p, va.y, a1);
                a2 = fmaf(p, vb.x, a2); a3 = fmaf(p, vb.y, a3);
                a4 = fmaf(p, vc.x, a4); a5 = fmaf(p, vc.y, a5);
                a6 = fmaf(p, vd.x, a6); a7 = fmaf(p, vd.y, a7);
                zacc += p;
            }
        }
        // reduce across the 8 slots (lane bits 0..2)
        #pragma unroll
        for (int m = 1; m < 8; m <<= 1) {
            a0 += __shfl_xor(a0, m, 64); a1 += __shfl_xor(a1, m, 64);
            a2 += __shfl_xor(a2, m, 64); a3 += __shfl_xor(a3, m, 64);
            a4 += __shfl_xor(a4, m, 64); a5 += __shfl_xor(a5, m, 64);
            a6 += __shfl_xor(a6, m, 64); a7 += __shfl_xor(a7, m, 64);
            zacc += __shfl_xor(zacc, m, 64);
        }
        if (slot == 0 && valid) {
            const float inv = (zacc == 0.0f) ? 0.0f : 1.0f / zacc;
            const float4 h0 = *(const float4*)(h + (size_t)n * 64 + hh * 8);
            const float4 h1 = *(const float4*)(h + (size_t)n * 64 + hh * 8 + 4);
            float xv[8];
            xv[0] = fmaf(a0, inv, h0.x); xv[1] = fmaf(a1, inv, h0.y);
            xv[2] = fmaf(a2, inv, h0.z); xv[3] = fmaf(a3, inv, h0.w);
            xv[4] = fmaf(a4, inv, h1.x); xv[5] = fmaf(a5, inv, h1.y);
            xv[6] = fmaf(a6, inv, h1.z); xv[7] = fmaf(a7, inv, h1.w);
            *(float4*)(x + (size_t)n * 64 + hh * 8)     =
                make_float4(xv[0], xv[1], xv[2], xv[3]);
            *(float4*)(x + (size_t)n * 64 + hh * 8 + 4) =
                make_float4(xv[4], xv[5], xv[6], xv[7]);
            #pragma unroll
            for (int j = 0; j < 8; ++j) {
                bsum[j] += xv[j];
                bsq[j]  += xv[j] * xv[j];
            }
        }
    }
    // block BN1 partials for this head's 8 channels
    __shared__ float lsm[32][8];
    __shared__ float lsq[32][8];
    if (slot == 0) {
        #pragma unroll
        for (int j = 0; j < 8; ++j) {
            lsm[wave * 8 + ns][j] = bsum[j];
            lsq[wave * 8 + ns][j] = bsq[j];
        }
    }
    __syncthreads();
    if (threadIdx.x < 8) {
        const int tt = threadIdx.x;
        float ss = 0.f, qq = 0.f;
        #pragma unroll
        for (int k = 0; k < 32; ++k) { ss += lsm[k][tt]; qq += lsq[k][tt]; }
        atomicAdd(s1 + hh * 8 + tt, ss);
        atomicAdd(sq1 + hh * 8 + tt, qq);
    }
}

// ---------------------------------------------------------------------------
// K5: fused BN1-finalize+apply + FFN + residual + BN2 partials.
// 512 thr, 64-row tile. W1/W2/hidden staged in LDS as fp16. 64 KB LDS.
// ---------------------------------------------------------------------------
__global__ __launch_bounds__(512, 4) void ffn_kernel(
    const float* __restrict__ x,
    const float* __restrict__ s1, const float* __restrict__ sq1,
    const float* __restrict__ g1, const float* __restrict__ b1,
    const float* __restrict__ W1, const float* __restrict__ bb1,
    const float* __restrict__ W2, const float* __restrict__ bb2,
    float* __restrict__ y, float* __restrict__ s2, float* __restrict__ sq2)
{
    __shared__ __half W1h[64][128];   // 16 KB (also reused as BN2 scratch)
    __shared__ __half W2h[128][64];   // 16 KB
    __shared__ float  xs[64][64];     // 16 KB
    __shared__ __half ts[64][128];    // 16 KB

    const int t  = threadIdx.x;
    const int tx = t & 15;
    const int ty = t >> 4;
    const int row0 = blockIdx.x * 64;

    {
        __half2* w1p = (__half2*)&W1h[0][0];
        __half2* w2p = (__half2*)&W2h[0][0];
        #pragma unroll
        for (int k = 0; k < 4; ++k) {
            const int i = t + k * 512;
            const float4 w1 = *(const float4*)(W1 + i * 4);
            w1p[i * 2]     = __floats2half2_rn(w1.x, w1.y);
            w1p[i * 2 + 1] = __floats2half2_rn(w1.z, w1.w);
            const float4 w2 = *(const float4*)(W2 + i * 4);
            w2p[i * 2]     = __floats2half2_rn(w2.x, w2.y);
            w2p[i * 2 + 1] = __floats2half2_rn(w2.z, w2.w);
        }
    }

    {
        const int c4 = tx * 4;
        const float4 ssum = *(const float4*)(s1 + c4);
        const float4 sqs  = *(const float4*)(sq1 + c4);
        const float4 gg   = *(const float4*)(g1 + c4);
        const float4 bb   = *(const float4*)(b1 + c4);
        float4 mm, rr, A, C;
        mm.x = ssum.x * INV_N; mm.y = ssum.y * INV_N;
        mm.z = ssum.z * INV_N; mm.w = ssum.w * INV_N;
        rr.x = rsqrtf(sqs.x * INV_N - mm.x * mm.x + EPS_BN);
        rr.y = rsqrtf(sqs.y * INV_N - mm.y * mm.y + EPS_BN);
        rr.z = rsqrtf(sqs.z * INV_N - mm.z * mm.z + EPS_BN);
        rr.w = rsqrtf(sqs.w * INV_N - mm.w * mm.w + EPS_BN);
        A.x = rr.x * gg.x; C.x = bb.x - mm.x * A.x;
        A.y = rr.y * gg.y; C.y = bb.y - mm.y * A.y;
        A.z = rr.z * gg.z; C.z = bb.z - mm.z * A.z;
        A.w = rr.w * gg.w; C.w = bb.w - mm.w * A.w;
        #pragma unroll
        for (int k = 0; k < 2; ++k) {
            const int i = t + k * 512;
            const int r = i >> 4;
            float4 v = make_float4(0.f, 0.f, 0.f, 0.f);
            if (row0 + r < N_NODES) {
                const float4 xv = *(const float4*)(x + (size_t)(row0 + r) * 64 + c4);
                v.x = fmaf(xv.x, A.x, C.x);
                v.y = fmaf(xv.y, A.y, C.y);
                v.z = fmaf(xv.z, A.z, C.z);
                v.w = fmaf(xv.w, A.w, C.w);
            }
            *(float4*)(&xs[r][c4]) = v;
        }
    }
    __syncthreads();

    const int r0 = ty * 2, r1 = r0 + 1;

    {
        const int cA = tx * 4, cB = 64 + tx * 4;
        float4 aA0 = make_float4(0,0,0,0), aA1 = aA0, aB0 = aA0, aB1 = aA0;
        #pragma unroll 4
        for (int c = 0; c < 64; ++c) {
            const __half2* wAp = (const __half2*)&W1h[c][cA];
            const __half2* wBp = (const __half2*)&W1h[c][cB];
            const float2 wa0 = __half22float2(wAp[0]);
            const float2 wa1 = __half22float2(wAp[1]);
            const float2 wb0 = __half22float2(wBp[0]);
            const float2 wb1 = __half22float2(wBp[1]);
            const float x0 = xs[r0][c];
            const float x1 = xs[r1][c];
            aA0.x = fmaf(x0, wa0.x, aA0.x); aA0.y = fmaf(x0, wa0.y, aA0.y);
            aA0.z = fmaf(x0, wa1.x, aA0.z); aA0.w = fmaf(x0, wa1.y, aA0.w);
            aA1.x = fmaf(x1, wa0.x, aA1.x); aA1.y = fmaf(x1, wa0.y, aA1.y);
            aA1.z = fmaf(x1, wa1.x, aA1.z); aA1.w = fmaf(x1, wa1.y, aA1.w);
            aB0.x = fmaf(x0, wb0.x, aB0.x); aB0.y = fmaf(x0, wb0.y, aB0.y);
            aB0.z = fmaf(x0, wb1.x, aB0.z); aB0.w = fmaf(x0, wb1.y, aB0.w);
            aB1.x = fmaf(x1, wb0.x, aB1.x); aB1.y = fmaf(x1, wb0.y, aB1.y);
            aB1.z = fmaf(x1, wb1.x, aB1.z); aB1.w = fmaf(x1, wb1.y, aB1.w);
        }
        const float4 b1A = *(const float4*)(bb1 + cA);
        const float4 b1B = *(const float4*)(bb1 + cB);
        aA0.x = fmaxf(aA0.x + b1A.x, 0.f); aA0.y = fmaxf(aA0.y + b1A.y, 0.f);
        aA0.z = fmaxf(aA0.z + b1A.z, 0.f); aA0.w = fmaxf(aA0.w + b1A.w, 0.f);
        aA1.x = fmaxf(aA1.x + b1A.x, 0.f); aA1.y = fmaxf(aA1.y + b1A.y, 0.f);
        aA1.z = fmaxf(aA1.z + b1A.z, 0.f); aA1.w = fmaxf(aA1.w + b1A.w, 0.f);
        aB0.x = fmaxf(aB0.x + b1B.x, 0.f); aB0.y = fmaxf(aB0.y + b1B.y, 0.f);
        aB0.z = fmaxf(aB0.z + b1B.z, 0.f); aB0.w = fmaxf(aB0.w + b1B.w, 0.f);
        aB1.x = fmaxf(aB1.x + b1B.x, 0.f); aB1.y = fmaxf(aB1.y + b1B.y, 0.f);
        aB1.z = fmaxf(aB1.z + b1B.z, 0.f); aB1.w = fmaxf(aB1.w + b1B.w, 0.f);
        *(__half2*)&ts[r0][cA]     = __floats2half2_rn(aA0.x, aA0.y);
        *(__half2*)&ts[r0][cA + 2] = __floats2half2_rn(aA0.z, aA0.w);
        *(__half2*)&ts[r1][cA]     = __floats2half2_rn(aA1.x, aA1.y);
        *(__half2*)&ts[r1][cA + 2] = __floats2half2_rn(aA1.z, aA1.w);
        *(__half2*)&ts[r0][cB]     = __floats2half2_rn(aB0.x, aB0.y);
        *(__half2*)&ts[r0][cB + 2] = __floats2half2_rn(aB0.z, aB0.w);
        *(__half2*)&ts[r1][cB]     = __floats2half2_rn(aB1.x, aB1.y);
        *(__half2*)&ts[r1][cB + 2] = __floats2half2_rn(aB1.z, aB1.w);
    }
    __syncthreads();

    float4 s = make_float4(0,0,0,0), q = s;
    {
        const int c4 = tx * 4;
        float4 y0 = make_float4(0,0,0,0), y1 = y0;
        #pragma unroll 4
        for (int k = 0; k < 128; ++k) {
            const __half2* wp = (const __half2*)&W2h[k][c4];
            const float2 wa = __half22float2(wp[0]);
            const float2 wb = __half22float2(wp[1]);
            const float T0 = __half2float(ts[r0][k]);
            const float T1 = __half2float(ts[r1][k]);
            y0.x = fmaf(T0, wa.x, y0.x); y0.y = fmaf(T0, wa.y, y0.y);
            y0.z = fmaf(T0, wb.x, y0.z); y0.w = fmaf(T0, wb.y, y0.w);
            y1.x = fmaf(T1, wa.x, y1.x); y1.y = fmaf(T1, wa.y, y1.y);
            y1.z = fmaf(T1, wb.x, y1.z); y1.w = fmaf(T1, wb.y, y1.w);
        }
        const float4 bb = *(const float4*)(bb2 + c4);
        const float4 h0 = *(const float4*)(&xs[r0][c4]);
        const float4 h1v = *(const float4*)(&xs[r1][c4]);
        y0.x += bb.x + h0.x;  y0.y += bb.y + h0.y;
        y0.z += bb.z + h0.z;  y0.w += bb.w + h0.w;
        y1.x += bb.x + h1v.x; y1.y += bb.y + h1v.y;
        y1.z += bb.z + h1v.z; y1.w += bb.w + h1v.w;

        const bool v0 = (row0 + r0) < N_NODES;
        const bool v1 = (row0 + r1) < N_NODES;
        if (v0) *(float4*)(y + (size_t)(row0 + r0) * 64 + c4) = y0;
        if (v1) *(float4*)(y + (size_t)(row0 + r1) * 64 + c4) = y1;

        if (v0) {
            s.x += y0.x; s.y += y0.y; s.z += y0.z; s.w += y0.w;
            q.x += y0.x*y0.x; q.y += y0.y*y0.y; q.z += y0.z*y0.z; q.w += y0.w*y0.w;
        }
        if (v1) {
            s.x += y1.x; s.y += y1.y; s.z += y1.z; s.w += y1.w;
            q.x += y1.x*y1.x; q.y += y1.y*y1.y; q.z += y1.z*y1.z; q.w += y1.w*y1.w;
        }
    }
    {
        float* red = (float*)&W1h[0][0];
        const int c4 = tx * 4;
        *(float4*)(red + ty * 64 + c4)        = s;
        *(float4*)(red + (32 + ty) * 64 + c4) = q;
    }
    __syncthreads();
    if (t < 64) {
        const float* red = (const float*)&W1h[0][0];
        float ss = 0.f, qq = 0.f;
        #pragma unroll
        for (int k = 0; k < 32; ++k) {
            ss += red[k * 64 + t];
            qq += red[(32 + k) * 64 + t];
        }
        atomicAdd(s2 + t, ss);
        atomicAdd(sq2 + t, qq);
    }
}

// ---------------------------------------------------------------------------
// K6: BN2 finalize + apply in place on y, float4.
// ---------------------------------------------------------------------------
__global__ __launch_bounds__(256) void bn2_apply_kernel(
    float* __restrict__ y,
    const float* __restrict__ s2, const float* __restrict__ sq2,
    const float* __restrict__ g2, const float* __restrict__ b2)
{
    const int c4 = (threadIdx.x & 15) * 4;
    const float4 ssum = *(const float4*)(s2 + c4);
    const float4 sqs  = *(const float4*)(sq2 + c4);
    const float4 gg   = *(const float4*)(g2 + c4);
    const float4 bb   = *(const float4*)(b2 + c4);
    float4 mm, rr, A, C;
    mm.x = ssum.x * INV_N; mm.y = ssum.y * INV_N;
    mm.z = ssum.z * INV_N; mm.w = ssum.w * INV_N;
    rr.x = rsqrtf(sqs.x * INV_N - mm.x * mm.x + EPS_BN);
    rr.y = rsqrtf(sqs.y * INV_N - mm.y * mm.y + EPS_BN);
    rr.z = rsqrtf(sqs.z * INV_N - mm.z * mm.z + EPS_BN);
    rr.w = rsqrtf(sqs.w * INV_N - mm.w * mm.w + EPS_BN);
    A.x = rr.x * gg.x; C.x = bb.x - mm.x * A.x;
    A.y = rr.y * gg.y; C.y = bb.y - mm.y * A.y;
    A.z = rr.z * gg.z; C.z = bb.z - mm.z * A.z;
    A.w = rr.w * gg.w; C.w = bb.w - mm.w * A.w;

    const int total4 = N_NODES * 16;
    const int stride = gridDim.x * blockDim.x;    // multiple of 16
    for (int i = blockIdx.x * blockDim.x + threadIdx.x; i < total4; i += stride) {
        float4 v = *((float4*)y + i);
        v.x = fmaf(v.x, A.x, C.x);
        v.y = fmaf(v.y, A.y, C.y);
        v.z = fmaf(v.z, A.z, C.z);
        v.w = fmaf(v.w, A.w, C.w);
        *((float4*)y + i) = v;
    }
}

extern "C" void kernel_launch(void* const* d_in, const int* in_sizes, int n_in,
                              void* d_out, int out_size, void* d_ws, size_t ws_size,
                              hipStream_t stream)
{
    const float* h   = (const float*)d_in[0];
    const int*   src = (const int*)d_in[1];
    const int*   dst = (const int*)d_in[2];
    const float* Wq  = (const float*)d_in[3];
    const float* bq  = (const float*)d_in[4];
    const float* Wk  = (const float*)d_in[5];
    const float* bk  = (const float*)d_in[6];
    const float* Wv  = (const float*)d_in[7];
    const float* bv  = (const float*)d_in[8];
    const float* g1  = (const float*)d_in[9];
    const float* b1  = (const float*)d_in[10];
    const float* W1  = (const float*)d_in[11];
    const float* bb1 = (const float*)d_in[12];
    const float* W2  = (const float*)d_in[13];
    const float* bb2 = (const float*)d_in[14];
    const float* g2  = (const float*)d_in[15];
    const float* b2  = (const float*)d_in[16];
    float* out = (float*)d_out;

    float* ws = (float*)d_ws;
    const size_t ND = (size_t)N_NODES * 64;
    float* Q  = ws;            // reused as x (per-head ranges, same-block order)
    __half* KV = (__half*)(ws + ND);   // fp16 KV[8][N][16]
    float* x  = Q;
    unsigned short* srcSorted = (unsigned short*)(ws + 3 * ND);  // E u16
    int* count     = (int*)(srcSorted + E_EDGES);  // N   (zeroed)
    float* st      = (float*)(count + N_NODES);    // 512 floats (zeroed)
    int* rowStart  = (int*)(st + 512);             // N+1
    int* cursor    = rowStart + N_NODES + 1;       // N
    int* blockSums = cursor + N_NODES;             // SCAN_BLOCKS
    float* s1 = st,       *sq1 = st + 64;
    float* s2 = st + 256, *sq2 = st + 320;

    hipMemsetAsync(count, 0, (N_NODES + 512) * sizeof(int), stream);

    qkv_hist_kernel<<<QKV_BLOCKS + HIST_BLOCKS, 256, 0, stream>>>(
        h, Wq, bq, Wk, bk, Wv, bv, Q, KV, dst, count);
    scanA_kernel<<<SCAN_BLOCKS, 256, 0, stream>>>(count, rowStart, blockSums);
    scanBC_kernel<<<SCAN_BLOCKS, 256, 0, stream>>>(rowStart, cursor, blockSums);
    scatter_kernel<<<(E_EDGES + 511) / 512, 256, 0, stream>>>(
        src, dst, cursor, srcSorted);
    gather_edge_kernel<<<1024, 256, 0, stream>>>(h, Q, KV, rowStart, srcSorted,
                                                 x, s1, sq1);
    ffn_kernel<<<(N_NODES + 63) / 64, 512, 0, stream>>>(
        x, s1, sq1, g1, b1, W1, bb1, W2, bb2, out, s2, sq2);
    bn2_apply_kernel<<<2048, 256, 0, stream>>>(out, s2, sq2, g2, b2);
}